// Round 14
// baseline (976.338 us; speedup 1.0000x reference)
//
#include <hip/hip_runtime.h>

#define N_NODES 50000
#define DIM0 35
#define BGRAPH 128
#define TSEQ 140
#define EPSBN 1e-5f
#define E_TOTAL 400000
#define E_INTRA 300000
#define E_INTER 100000
#define FC1_OUT 4340

typedef __attribute__((ext_vector_type(8))) short s8v;
typedef __attribute__((ext_vector_type(4))) short s4v;
typedef __attribute__((ext_vector_type(4))) float f32x4;

static __device__ __forceinline__ unsigned short bf16_rne(float x) {
    unsigned int u = __float_as_uint(x);
    unsigned int r = (u + 0x7FFFu + ((u >> 16) & 1u)) >> 16;
    return (unsigned short)r;
}
static __device__ __forceinline__ void bf16_split(float x, unsigned short& h, unsigned short& l) {
    h = bf16_rne(x);
    float hf = __uint_as_float(((unsigned int)h) << 16);
    l = bf16_rne(x - hf);
}

static __device__ __forceinline__ void edge_sd(int e, const int* intra, const int* inter, int& s, int& d) {
    if (e < E_INTRA) { s = intra[e]; d = intra[E_INTRA + e]; }
    else { int k = e - E_INTRA; s = inter[k]; d = inter[E_INTER + k]; }
}

__global__ void k_init(int* cnt, int* cursor, float* out, const float* bfc2, float* bnsumAll, float* bv4) {
    int i = blockIdx.x * 256 + threadIdx.x;
    if (i < N_NODES) { cnt[i] = 0; cursor[i] = 0; }
    if (i < BGRAPH) out[i] = bfc2[0];
    if (i < 5 * 1024) bnsumAll[i] = 0.f;
    if (i < 256) bv4[i] = 0.f;
}

__global__ void k_deg(const int* intra, const int* inter, int* cnt) {
    int e = blockIdx.x * 256 + threadIdx.x;
    if (e >= E_TOTAL) return;
    int s, d; edge_sd(e, intra, inter, s, d);
    atomicAdd(&cnt[d], 1);
}

__global__ void k_scan1(const int* __restrict__ cnt, int* __restrict__ partial, int* __restrict__ blocksum,
                        float* __restrict__ dinv) {
    __shared__ int buf[256];
    int t = threadIdx.x;
    int i = blockIdx.x * 256 + t;
    int v = (i < N_NODES) ? cnt[i] : 0;
    if (i < N_NODES) dinv[i] = rsqrtf(1.0f + (float)v);
    buf[t] = v;
    __syncthreads();
    for (int off = 1; off < 256; off <<= 1) {
        int add = (t >= off) ? buf[t - off] : 0;
        __syncthreads();
        buf[t] += add;
        __syncthreads();
    }
    if (i < N_NODES) partial[i] = buf[t];
    if (t == 255) blocksum[blockIdx.x] = buf[255];
}

__global__ void k_scan2(int* blocksum, int nb) {
    __shared__ int buf[256];
    int t = threadIdx.x;
    buf[t] = (t < nb) ? blocksum[t] : 0;
    __syncthreads();
    for (int off = 1; off < 256; off <<= 1) {
        int add = (t >= off) ? buf[t - off] : 0;
        __syncthreads();
        buf[t] += add;
        __syncthreads();
    }
    if (t < nb) blocksum[t] = buf[t];
}

__global__ void k_scan3(const int* __restrict__ partial, const int* __restrict__ blocksum, int* __restrict__ rowptr) {
    int b = blockIdx.x;
    int i = b * 256 + threadIdx.x;
    if (i == 0) rowptr[0] = 0;
    if (i < N_NODES) {
        int off = (b == 0) ? 0 : blocksum[b - 1];
        rowptr[i + 1] = partial[i] + off;
    }
}

__global__ void k_scatter(const int* intra, const int* inter, const int* rowptr,
                          int* cursor, const float* dinv, int* srcs, float* coef) {
    int e = blockIdx.x * 256 + threadIdx.x;
    if (e >= E_TOTAL) return;
    int s, d; edge_sd(e, intra, inter, s, d);
    int p = rowptr[d] + atomicAdd(&cursor[d], 1);
    srcs[p] = s;
    coef[p] = dinv[s] * dinv[d];
}

// wave-per-node aggregate for d=35 (2-way ILP edge loop)
__global__ __launch_bounds__(256) void k_agg_small(const float* __restrict__ X, float* __restrict__ Z,
        const int* __restrict__ rowptr, const int* __restrict__ srcs, const float* __restrict__ coef,
        const float* __restrict__ dinv, const float* __restrict__ bias) {
    int wave = threadIdx.x >> 6, lane = threadIdx.x & 63;
    int i = blockIdx.x * 4 + wave;
    if (i >= N_NODES || lane >= DIM0) return;
    int b0 = __builtin_amdgcn_readfirstlane(rowptr[i]);
    int e1 = __builtin_amdgcn_readfirstlane(rowptr[i + 1]);
    float self = dinv[i] * dinv[i];
    float acc0 = X[(size_t)i * DIM0 + lane] * self;
    float acc1 = 0.f;
    if (bias) acc0 += bias[lane];
    int k = b0;
    for (; k + 1 < e1; k += 2) {
        int s0 = srcs[k], s1 = srcs[k + 1];
        float c0 = coef[k], c1 = coef[k + 1];
        acc0 += c0 * X[(size_t)s0 * DIM0 + lane];
        acc1 += c1 * X[(size_t)s1 * DIM0 + lane];
    }
    if (k < e1) acc0 += coef[k] * X[(size_t)srcs[k] * DIM0 + lane];
    Z[(size_t)i * DIM0 + lane] = acc0 + acc1;
}

// lane-group-per-node float4 aggregate. BN fold hoisted OUT of the edge loop:
//   Z = alpha (.) (self*x_i + sum cf*x_s) + beta * (self + sum cf) + bias
__global__ __launch_bounds__(256) void k_agg_vec(const float* __restrict__ X, float* __restrict__ Z,
        const int* __restrict__ rowptr, const int* __restrict__ srcs, const float* __restrict__ coef,
        const float* __restrict__ dinv, const float* __restrict__ alpha, const float* __restrict__ beta,
        const float* __restrict__ bias, int d, int lpshift) {
    int i = (blockIdx.x * 256 + threadIdx.x) >> lpshift;
    int lane_in = threadIdx.x & ((1 << lpshift) - 1);
    if (i >= N_NODES) return;
    int b0 = rowptr[i], e1 = rowptr[i + 1];
    if (lpshift == 6) {
        b0 = __builtin_amdgcn_readfirstlane(b0);
        e1 = __builtin_amdgcn_readfirstlane(e1);
    }
    float self = dinv[i] * dinv[i];
    int c = lane_in * 4;
    float4 xi = *(const float4*)&X[(size_t)i * d + c];
    float4 a0, a1;
    a0.x = self * xi.x; a0.y = self * xi.y; a0.z = self * xi.z; a0.w = self * xi.w;
    a1 = make_float4(0.f, 0.f, 0.f, 0.f);
    float cs0 = self, cs1 = 0.f;
    int k = b0;
    for (; k + 1 < e1; k += 2) {
        int s0 = srcs[k], s1 = srcs[k + 1];
        float c0 = coef[k], c1 = coef[k + 1];
        float4 x0 = *(const float4*)&X[(size_t)s0 * d + c];
        float4 x1 = *(const float4*)&X[(size_t)s1 * d + c];
        a0.x += c0 * x0.x; a0.y += c0 * x0.y; a0.z += c0 * x0.z; a0.w += c0 * x0.w;
        a1.x += c1 * x1.x; a1.y += c1 * x1.y; a1.z += c1 * x1.z; a1.w += c1 * x1.w;
        cs0 += c0; cs1 += c1;
    }
    if (k < e1) {
        int s0 = srcs[k];
        float c0 = coef[k];
        float4 x0 = *(const float4*)&X[(size_t)s0 * d + c];
        a0.x += c0 * x0.x; a0.y += c0 * x0.y; a0.z += c0 * x0.z; a0.w += c0 * x0.w;
        cs0 += c0;
    }
    float4 acc;
    acc.x = a0.x + a1.x; acc.y = a0.y + a1.y; acc.z = a0.z + a1.z; acc.w = a0.w + a1.w;
    float csum = cs0 + cs1;
    float4 z = acc;
    if (alpha) {
        float4 al = *(const float4*)&alpha[c];
        float4 be = *(const float4*)&beta[c];
        z.x = al.x * acc.x + be.x * csum;
        z.y = al.y * acc.y + be.y * csum;
        z.z = al.z * acc.z + be.z * csum;
        z.w = al.w * acc.w + be.w * csum;
    }
    if (bias) {
        float4 bi = *(const float4*)&bias[c];
        z.x += bi.x; z.y += bi.y; z.z += bi.z; z.w += bi.w;
    }
    *(float4*)&Z[(size_t)i * d + c] = z;
}

// small fp32 GEMM (64x64 tile) with optional BN fold + relu on A-load.
__global__ __launch_bounds__(256) void k_gemm(const float* __restrict__ A, const float* __restrict__ W,
                                              const float* __restrict__ bias, float* __restrict__ C,
                                              int Mrows, int K, int Ncols, int relu,
                                              const float* __restrict__ alphaA, const float* __restrict__ betaA,
                                              int reluA) {
    __shared__ float As[64][17];
    __shared__ float Ws[16][65];
    int tid = threadIdx.x;
    int tx = tid & 15, ty = tid >> 4;
    int row0 = blockIdx.y * 64, col0 = blockIdx.x * 64;
    float acc[4][4] = {};
    for (int k0 = 0; k0 < K; k0 += 16) {
        for (int l = tid; l < 1024; l += 256) {
            int m = l >> 4, kk = l & 15;
            int r = row0 + m, k = k0 + kk;
            float v = 0.f;
            if (r < Mrows && k < K) {
                v = A[(size_t)r * K + k];
                if (alphaA) {
                    v = alphaA[k] * v + betaA[k];
                    if (reluA) v = fmaxf(v, 0.f);
                }
            }
            As[m][kk] = v;
        }
        for (int l = tid; l < 1024; l += 256) {
            int kk = l >> 6, n = l & 63;
            int k = k0 + kk, c = col0 + n;
            Ws[kk][n] = (k < K && c < Ncols) ? W[(size_t)k * Ncols + c] : 0.f;
        }
        __syncthreads();
#pragma unroll
        for (int kk = 0; kk < 16; ++kk) {
            float a[4], w[4];
#pragma unroll
            for (int i2 = 0; i2 < 4; ++i2) a[i2] = As[ty * 4 + i2][kk];
#pragma unroll
            for (int j = 0; j < 4; ++j) w[j] = Ws[kk][tx * 4 + j];
#pragma unroll
            for (int i2 = 0; i2 < 4; ++i2)
#pragma unroll
                for (int j = 0; j < 4; ++j)
                    acc[i2][j] += a[i2] * w[j];
        }
        __syncthreads();
    }
    for (int i2 = 0; i2 < 4; ++i2) {
        int r = row0 + ty * 4 + i2;
        if (r >= Mrows) continue;
        for (int j = 0; j < 4; ++j) {
            int c = col0 + tx * 4 + j;
            if (c >= Ncols) continue;
            float v = acc[i2][j];
            if (bias) v += bias[c];
            if (relu) v = fmaxf(v, 0.f);
            C[(size_t)r * Ncols + c] = v;
        }
    }
}

// Preprocess W[K][N] fp32 -> MFMA-fragment bf16 hi/lo; optional per-k rowscale.
__global__ void k_wprep(const float* __restrict__ W, unsigned short* __restrict__ Wf, int K, int Ncols,
                        const float* __restrict__ rowscale) {
    int gid = blockIdx.x * 256 + threadIdx.x;
    int KT = K >> 5;
    int total = (Ncols >> 4) * KT * 64;
    if (gid >= total) return;
    int lane = gid & 63;
    int f = gid >> 6;
    int kt = f % KT, ntile = f / KT;
    int n = ntile * 16 + (lane & 15);
    int kb = kt * 32 + (lane >> 4) * 8;
    size_t base = (size_t)f * 1024 + lane * 8;
#pragma unroll
    for (int j = 0; j < 8; ++j) {
        float v = W[(size_t)(kb + j) * Ncols + n];
        if (rowscale) v *= rowscale[kb + j];
        unsigned short h, l;
        bf16_split(v, h, l);
        Wf[base + j] = h;
        Wf[base + 512 + j] = l;
    }
}

// bv[c] += sum_{k in block's 16-row slice} beta[k] * W[k][c]
__global__ void k_bnbias(const float* __restrict__ W, const float* __restrict__ beta,
                         float* __restrict__ bv, int K, int Ncols) {
    int c = threadIdx.x;
    if (c >= Ncols) return;
    int k0 = blockIdx.x * 16;
    float acc = 0.f;
#pragma unroll
    for (int k = 0; k < 16; ++k) acc += beta[k0 + k] * W[(size_t)(k0 + k) * Ncols + c];
    atomicAdd(&bv[c], acc);
}

// MFMA GEMM, SINGLE-buffered LDS (20.5 KB -> ~7 blocks/CU) for occupancy-driven
// latency hiding; A-register prefetch at distance 1 preserved (loads for kt+1
// issued right after store_chunk(kt) consumes the regs, so they fly under kt's
// MFMAs). 128x128 tile, 4 waves 2x2. fp32 A in (optional BN fold), bf16 hi/lo
// split in staging, fp32 C out, optional fused BN stats.
__global__ __launch_bounds__(256) void k_gemm_mfma(
    const float* __restrict__ A, const unsigned short* __restrict__ Wf,
    const float* __restrict__ bias, float* __restrict__ C,
    int Mrows, int K, int Ncols, int relu,
    const float* __restrict__ alphaA, const float* __restrict__ betaA,
    float* __restrict__ bnsum) {
    __shared__ unsigned short As[2][128][40];  // [hi|lo][m][k] 20480 B
    int tid = threadIdx.x;
    int lane = tid & 63, wave = tid >> 6;
    int wm = wave >> 1, wn = wave & 1;
    int row0 = blockIdx.y * 128;
    int nt0 = blockIdx.x * 8;
    int KT = K >> 5;

    f32x4 acc[4][4];
#pragma unroll
    for (int a = 0; a < 4; ++a)
#pragma unroll
        for (int b = 0; b < 4; ++b) acc[a][b] = (f32x4)0.f;

    float4 reg[4];
    auto load_chunk = [&](int kt) {
#pragma unroll
        for (int l = 0; l < 4; ++l) {
            int i = tid + l * 256;
            int m = i >> 3, kv = (i & 7) * 4;
            int r = row0 + m;
            float4 v = make_float4(0.f, 0.f, 0.f, 0.f);
            if (r < Mrows) v = *(const float4*)&A[(size_t)r * K + kt * 32 + kv];
            reg[l] = v;
        }
    };
    auto store_chunk = [&](int kt) {
#pragma unroll
        for (int l = 0; l < 4; ++l) {
            int i = tid + l * 256;
            int m = i >> 3, kv = (i & 7) * 4;
            float4 v = reg[l];
            if (alphaA) {
                int kg = kt * 32 + kv;
                float4 al = *(const float4*)&alphaA[kg];
                float4 be = *(const float4*)&betaA[kg];
                v.x = al.x * v.x + be.x;
                v.y = al.y * v.y + be.y;
                v.z = al.z * v.z + be.z;
                v.w = al.w * v.w + be.w;
            }
            unsigned short h0, l0, h1, l1, h2, l2, h3, l3;
            bf16_split(v.x, h0, l0); bf16_split(v.y, h1, l1);
            bf16_split(v.z, h2, l2); bf16_split(v.w, h3, l3);
            s4v hv = {(short)h0, (short)h1, (short)h2, (short)h3};
            s4v lv = {(short)l0, (short)l1, (short)l2, (short)l3};
            *(s4v*)&As[0][m][kv] = hv;
            *(s4v*)&As[1][m][kv] = lv;
        }
    };

    int mrow = wm * 64 + (lane & 15);
    int koff = (lane >> 4) * 8;

    load_chunk(0);
    for (int kt = 0; kt < KT; ++kt) {
        __syncthreads();                 // previous compute done; LDS free
        store_chunk(kt);                 // consumes reg (waits on its loads)
        if (kt + 1 < KT) load_chunk(kt + 1);  // next A loads fly under this kt's MFMAs
        __syncthreads();                 // staging visible
        s8v bh[4], bl[4];
#pragma unroll
        for (int nt = 0; nt < 4; ++nt) {
            int ntg = nt0 + wn * 4 + nt;
            size_t fb = ((size_t)(ntg * KT + kt)) * 1024 + lane * 8;
            bh[nt] = *(const s8v*)&Wf[fb];
            bl[nt] = *(const s8v*)&Wf[fb + 512];
        }
        s8v ah[4], alo[4];
#pragma unroll
        for (int mt = 0; mt < 4; ++mt) {
            ah[mt]  = *(const s8v*)&As[0][mrow + mt * 16][koff];
            alo[mt] = *(const s8v*)&As[1][mrow + mt * 16][koff];
        }
#pragma unroll
        for (int nt = 0; nt < 4; ++nt)
#pragma unroll
            for (int mt = 0; mt < 4; ++mt) {
                acc[mt][nt] = __builtin_amdgcn_mfma_f32_16x16x32_bf16(ah[mt], bh[nt], acc[mt][nt], 0, 0, 0);
                acc[mt][nt] = __builtin_amdgcn_mfma_f32_16x16x32_bf16(ah[mt], bl[nt], acc[mt][nt], 0, 0, 0);
                acc[mt][nt] = __builtin_amdgcn_mfma_f32_16x16x32_bf16(alo[mt], bh[nt], acc[mt][nt], 0, 0, 0);
            }
    }

    // epilogue: nt innermost so the wave's 4 x 64B stores per row are contiguous in time
    int cbase = (nt0 + wn * 4) * 16 + (lane & 15);
    float bia[4];
#pragma unroll
    for (int nt = 0; nt < 4; ++nt) bia[nt] = bias ? bias[cbase + nt * 16] : 0.f;
    float s1[4] = {0.f, 0.f, 0.f, 0.f}, s2[4] = {0.f, 0.f, 0.f, 0.f};
#pragma unroll
    for (int mt = 0; mt < 4; ++mt) {
        int rbase = row0 + wm * 64 + mt * 16 + (lane >> 4) * 4;
#pragma unroll
        for (int r = 0; r < 4; ++r) {
            int rg = rbase + r;
            if (rg < Mrows) {
#pragma unroll
                for (int nt = 0; nt < 4; ++nt) {
                    float v = acc[mt][nt][r] + bia[nt];
                    if (relu) v = fmaxf(v, 0.f);
                    C[(size_t)rg * Ncols + cbase + nt * 16] = v;
                    s1[nt] += v; s2[nt] += v * v;
                }
            }
        }
    }
    if (bnsum) {
#pragma unroll
        for (int nt = 0; nt < 4; ++nt) {
            float a = s1[nt], b = s2[nt];
            a += __shfl_xor(a, 16, 64);
            a += __shfl_xor(a, 32, 64);
            b += __shfl_xor(b, 16, 64);
            b += __shfl_xor(b, 32, 64);
            if (lane < 16) {
                atomicAdd(&bnsum[cbase + nt * 16], a);
                atomicAdd(&bnsum[Ncols + cbase + nt * 16], b);
            }
        }
    }
}

// scalar BN stats; launch <<<d, 256>>> so each thread owns one column slot
__global__ void k_bn_stats(const float* __restrict__ X, float* sums, int d) {
    long long total = (long long)N_NODES * d;
    int G = gridDim.x * blockDim.x;
    int gid = blockIdx.x * blockDim.x + threadIdx.x;
    int c = gid % d;
    float s1 = 0.f, s2 = 0.f;
    for (long long i = gid; i < total; i += G) {
        float v = X[i];
        s1 += v; s2 += v * v;
    }
    atomicAdd(&sums[c], s1);
    atomicAdd(&sums[d + c], s2);
}

__global__ void k_bn_final(const float* sums, const float* g, const float* be,
                           float* alpha, float* beta, int d) {
    int c = threadIdx.x;
    if (c >= d) return;
    float mean = sums[c] / (float)N_NODES;
    float var = sums[d + c] / (float)N_NODES - mean * mean;
    float a = g[c] * rsqrtf(var + EPSBN);
    alpha[c] = a;
    beta[c] = be[c] - mean * a;
}

__global__ void k_pool(const float* __restrict__ h, const int* __restrict__ split,
                       const int* __restrict__ batch, float* lig, float* pro,
                       const float* __restrict__ alpha, const float* __restrict__ beta) {
    int b = blockIdx.x;
    __shared__ float sl[DIM0], sp[DIM0];
    __shared__ int s_start, s_end;
    if (threadIdx.x < DIM0) { sl[threadIdx.x] = 0.f; sp[threadIdx.x] = 0.f; }
    if (threadIdx.x == 0) {
        int lo = 0, hi = N_NODES;
        while (lo < hi) { int mid = (lo + hi) >> 1; if (batch[mid] < b) lo = mid + 1; else hi = mid; }
        s_start = lo;
        hi = N_NODES;
        while (lo < hi) { int mid = (lo + hi) >> 1; if (batch[mid] < b + 1) lo = mid + 1; else hi = mid; }
        s_end = lo;
    }
    __syncthreads();
    int start = s_start, end = s_end;
    for (int k = threadIdx.x; k < (end - start) * DIM0; k += blockDim.x) {
        int node = start + k / DIM0;
        int c = k % DIM0;
        float v = alpha[c] * h[(size_t)node * DIM0 + c] + beta[c];
        if (split[node] == 1) atomicAdd(&sp[c], v);
        else atomicAdd(&sl[c], v);
    }
    __syncthreads();
    if (threadIdx.x < DIM0) {
        lig[b * DIM0 + threadIdx.x] = sl[threadIdx.x];
        pro[b * DIM0 + threadIdx.x] = sp[threadIdx.x];
    }
}

__global__ __launch_bounds__(192) void k_lstm(
    const float* __restrict__ lig, const float* __restrict__ pro,
    const float* __restrict__ Wih_f, const float* __restrict__ Whh_f,
    const float* __restrict__ bih_f, const float* __restrict__ bhh_f,
    const float* __restrict__ Wih_b, const float* __restrict__ Whh_b,
    const float* __restrict__ bih_b, const float* __restrict__ bhh_b,
    float* __restrict__ outb) {
    int blk = blockIdx.x;
    int dir = blk >> 7;
    int b = blk & 127;
    const float* Wih = dir ? Wih_b : Wih_f;
    const float* Whh = dir ? Whh_b : Whh_f;
    const float* bih = dir ? bih_b : bih_f;
    const float* bhh = dir ? bhh_b : bhh_f;

    __shared__ float h_lds[DIM0];
    __shared__ float x_lds[2][DIM0];
    __shared__ float gate_lds[4 * DIM0];
    int t = threadIdx.x;
    float wih[DIM0], whh[DIM0], bsum = 0.f;
    if (t < 4 * DIM0) {
#pragma unroll
        for (int j = 0; j < DIM0; ++j) { wih[j] = Wih[t * DIM0 + j]; whh[j] = Whh[t * DIM0 + j]; }
        bsum = bih[t] + bhh[t];
    }
    if (t < DIM0) {
        x_lds[0][t] = lig[b * DIM0 + t];
        x_lds[1][t] = pro[b * DIM0 + t];
        h_lds[t] = 0.f;
    }
    float c_reg = 0.f;
    __syncthreads();
    for (int step = 0; step < TSEQ; ++step) {
        int tt = dir ? (TSEQ - 1 - step) : step;
        if (t < 4 * DIM0) {
            float acc0 = bsum, acc1 = 0.f;
            if (tt < 2) {
#pragma unroll
                for (int j = 0; j < DIM0; ++j) acc0 += wih[j] * x_lds[tt][j];
            }
#pragma unroll
            for (int j = 0; j < DIM0 - 1; j += 2) {
                acc0 += whh[j] * h_lds[j];
                acc1 += whh[j + 1] * h_lds[j + 1];
            }
            acc0 += whh[DIM0 - 1] * h_lds[DIM0 - 1];
            gate_lds[t] = acc0 + acc1;
        }
        __syncthreads();
        if (t < DIM0) {
            float gi = gate_lds[t], gf = gate_lds[DIM0 + t];
            float gg = gate_lds[2 * DIM0 + t], go = gate_lds[3 * DIM0 + t];
            float si = 1.f / (1.f + expf(-gi));
            float sf = 1.f / (1.f + expf(-gf));
            float so = 1.f / (1.f + expf(-go));
            c_reg = sf * c_reg + si * tanhf(gg);
            float hv = so * tanhf(c_reg);
            h_lds[t] = hv;
            outb[((size_t)b * TSEQ + tt) * 70 + dir * DIM0 + t] = hv;
        }
        __syncthreads();
    }
}

__global__ void k_concatW(const float* __restrict__ Wq, const float* __restrict__ bq,
                          const float* __restrict__ Wk, const float* __restrict__ bk,
                          const float* __restrict__ Wv, const float* __restrict__ bv,
                          float* __restrict__ Wcat, float* __restrict__ bcat) {
    int idx = blockIdx.x * 256 + threadIdx.x;
    if (idx < 70 * 210) {
        int k = idx / 210, col = idx % 210;
        int g = col / 70, j = col % 70;
        const float* Wsrc = (g == 0) ? Wq : ((g == 1) ? Wk : Wv);
        Wcat[idx] = Wsrc[k * 70 + j];
    }
    if (idx < 210) {
        int g = idx / 70, j = idx % 70;
        const float* bsrc = (g == 0) ? bq : ((g == 1) ? bk : bv);
        bcat[idx] = bsrc[j];
    }
}

__global__ void k_attention(const float* __restrict__ qkv, float* __restrict__ osm) {
    int b = blockIdx.x;
    __shared__ float q0[70], q1[70], s[TSEQ];
    __shared__ float s00_s, s01_s, ssum_s;
    int t = threadIdx.x;
    const float* base = qkv + (size_t)b * TSEQ * 210;
    if (t < 70) {
        q0[t] = base[0 * 210 + t];
        q1[t] = base[1 * 210 + t];
    }
    __syncthreads();
    const float scale = rsqrtf(70.f);
    if (t < TSEQ) {
        const float* krow = base + (size_t)t * 210 + 70;
        float acc = 0.f;
        for (int j = 0; j < 70; ++j) acc += q1[j] * krow[j];
        s[t] = acc * scale;
    } else if (t == TSEQ || t == TSEQ + 1) {
        int kk = t - TSEQ;
        const float* krow = base + (size_t)kk * 210 + 70;
        float acc = 0.f;
        for (int j = 0; j < 70; ++j) acc += q0[j] * krow[j];
        if (kk) s01_s = acc * scale; else s00_s = acc * scale;
    }
    __syncthreads();
    if (t == 0) {
        float mx = -1e30f;
        for (int i = 0; i < TSEQ; ++i) if (i != 1) mx = fmaxf(mx, s[i]);
        float sum = 0.f;
        for (int i = 0; i < TSEQ; ++i) {
            float e = (i == 1) ? 0.f : expf(s[i] - mx);
            s[i] = e; sum += e;
        }
        ssum_s = sum;
    }
    __syncthreads();
    if (t < 70) {
        float inv = 1.f / ssum_s;
        float acc = 0.f;
        for (int i = 0; i < TSEQ; ++i) acc += s[i] * base[(size_t)i * 210 + 140 + t];
        float o1v = acc * inv;
        float m0 = fmaxf(s00_s, s01_s);
        float e0 = expf(s00_s - m0), e1 = expf(s01_s - m0);
        float w0 = e0 / (e0 + e1), w1 = e1 / (e0 + e1);
        float v0 = base[0 * 210 + 140 + t];
        float v1 = base[1 * 210 + 140 + t];
        osm[b * 210 + t] = w0 * v0 + w1 * v1;
        osm[b * 210 + 70 + t] = o1v;
        osm[b * 210 + 140 + t] = v1;
    }
}

// Wsum[j][c] = sum_{tt=2..139} Wfc1[tt*70+j][c]  -- float4 over c (no atomics)
__global__ void k_wsum(const float* __restrict__ Wfc1, float* __restrict__ Wsum) {
    const int C4 = FC1_OUT / 4;  // 1085
    int idx = blockIdx.x * 256 + threadIdx.x;
    if (idx >= 70 * C4) return;
    int j = idx / C4, c4 = idx % C4;
    int c = c4 * 4;
    float4 acc = make_float4(0.f, 0.f, 0.f, 0.f);
    for (int tt = 2; tt < TSEQ; ++tt) {
        float4 w = *(const float4*)&Wfc1[((size_t)(tt * 70 + j)) * FC1_OUT + c];
        acc.x += w.x; acc.y += w.y; acc.z += w.z; acc.w += w.w;
    }
    *(float4*)&Wsum[(size_t)j * FC1_OUT + c] = acc;
}

__global__ __launch_bounds__(256) void k_fc(const float* __restrict__ osm, const float* __restrict__ Wfc1,
                                            const float* __restrict__ Wsum, const float* __restrict__ bfc1,
                                            const float* __restrict__ Wfc2, float* __restrict__ out) {
    __shared__ float olds[8][210];
    __shared__ float wred[4][8];
    int g = blockIdx.y;
    int c = blockIdx.x * 256 + threadIdx.x;
    for (int l = threadIdx.x; l < 8 * 210; l += 256)
        olds[l / 210][l % 210] = osm[(g * 8 + l / 210) * 210 + (l % 210)];
    __syncthreads();
    float acc[8] = {};
    if (c < FC1_OUT) {
        for (int j = 0; j < 140; ++j) {
            float w = Wfc1[(size_t)j * FC1_OUT + c];
#pragma unroll
            for (int b = 0; b < 8; ++b) acc[b] = fmaf(olds[b][j], w, acc[b]);
        }
        for (int j = 0; j < 70; ++j) {
            float w = Wsum[(size_t)j * FC1_OUT + c];
#pragma unroll
            for (int b = 0; b < 8; ++b) acc[b] = fmaf(olds[b][140 + j], w, acc[b]);
        }
        float bb = bfc1[c], pw = Wfc2[c];
#pragma unroll
        for (int b = 0; b < 8; ++b) acc[b] = fmaxf(acc[b] + bb, 0.f) * pw;
    }
#pragma unroll
    for (int b = 0; b < 8; ++b) {
        acc[b] += __shfl_down(acc[b], 32, 64);
        acc[b] += __shfl_down(acc[b], 16, 64);
        acc[b] += __shfl_down(acc[b], 8, 64);
        acc[b] += __shfl_down(acc[b], 4, 64);
        acc[b] += __shfl_down(acc[b], 2, 64);
        acc[b] += __shfl_down(acc[b], 1, 64);
    }
    int wave = threadIdx.x >> 6;
    if ((threadIdx.x & 63) == 0)
#pragma unroll
        for (int b = 0; b < 8; ++b) wred[wave][b] = acc[b];
    __syncthreads();
    if (threadIdx.x < 8) {
        float t = wred[0][threadIdx.x] + wred[1][threadIdx.x] + wred[2][threadIdx.x] + wred[3][threadIdx.x];
        atomicAdd(&out[g * 8 + threadIdx.x], t);
    }
}

extern "C" void kernel_launch(void* const* d_in, const int* in_sizes, int n_in,
                              void* d_out, int out_size, void* d_ws, size_t ws_size,
                              hipStream_t stream) {
    const float* x = (const float*)d_in[0];
    const int* intra = (const int*)d_in[1];
    const int* inter = (const int*)d_in[2];
    const int* split = (const int*)d_in[3];
    const int* batch = (const int*)d_in[4];
    const float *W[5], *bW[5], *gW[5], *beW[5];
    for (int i = 0; i < 5; ++i) {
        W[i]   = (const float*)d_in[5 + 4 * i];
        bW[i]  = (const float*)d_in[6 + 4 * i];
        gW[i]  = (const float*)d_in[7 + 4 * i];
        beW[i] = (const float*)d_in[8 + 4 * i];
    }
    const float* Wih_f = (const float*)d_in[25];
    const float* Whh_f = (const float*)d_in[26];
    const float* bih_f = (const float*)d_in[27];
    const float* bhh_f = (const float*)d_in[28];
    const float* Wih_b = (const float*)d_in[29];
    const float* Whh_b = (const float*)d_in[30];
    const float* bih_b = (const float*)d_in[31];
    const float* bhh_b = (const float*)d_in[32];
    const float* Wq = (const float*)d_in[33];
    const float* bq = (const float*)d_in[34];
    const float* Wk = (const float*)d_in[35];
    const float* bk = (const float*)d_in[36];
    const float* Wv = (const float*)d_in[37];
    const float* bv = (const float*)d_in[38];
    const float* Wfc1 = (const float*)d_in[39];
    const float* bfc1 = (const float*)d_in[40];
    const float* Wfc2 = (const float*)d_in[41];
    const float* bfc2 = (const float*)d_in[42];

    char* p = (char*)d_ws;
    auto carve = [&](size_t bytes) {
        char* r = p;
        p += (bytes + 255) & ~(size_t)255;
        return r;
    };
    float* bufA = (float*)carve((size_t)N_NODES * 512 * 4);
    float* bufB = (float*)carve((size_t)N_NODES * 256 * 4);
    float* bufM = (float*)carve((size_t)N_NODES * 256 * 4);
    float* dinv = (float*)carve((size_t)N_NODES * 4);
    int* cnt    = (int*)carve((size_t)N_NODES * 4);
    int* rowptr = (int*)carve((size_t)(N_NODES + 1) * 4);
    int* cursor = (int*)carve((size_t)N_NODES * 4);
    int* scanp  = (int*)carve((size_t)N_NODES * 4);
    int* bsums  = (int*)carve(256 * 4);
    int* srcs   = (int*)carve((size_t)E_TOTAL * 4);
    float* coef = (float*)carve((size_t)E_TOTAL * 4);
    float* bnsumAll = (float*)carve(5 * 1024 * 4);
    float* alphaAll = (float*)carve(5 * 512 * 4);
    float* betaAll  = (float*)carve(5 * 512 * 4);
    float* bv4  = (float*)carve(256 * 4);
    float* lig = (float*)carve((size_t)BGRAPH * DIM0 * 4);
    float* pro = (float*)carve((size_t)BGRAPH * DIM0 * 4);
    float* outb = (float*)carve((size_t)BGRAPH * TSEQ * 70 * 4);
    float* qkvb = (float*)carve((size_t)BGRAPH * TSEQ * 210 * 4);
    float* Wcat = (float*)carve((size_t)70 * 210 * 4);
    float* bcat = (float*)carve(210 * 4);
    float* osm = (float*)carve((size_t)BGRAPH * 210 * 4);
    float* wsum = (float*)carve((size_t)70 * FC1_OUT * 4);
    unsigned short* Wf2 = (unsigned short*)carve((size_t)128 * 256 * 2 * 2);
    unsigned short* Wf3 = (unsigned short*)carve((size_t)256 * 512 * 2 * 2);
    unsigned short* Wf4 = (unsigned short*)carve((size_t)512 * 256 * 2 * 2);

    float* out = (float*)d_out;

    const int SCAN_B = (N_NODES + 255) / 256;

    k_init<<<(N_NODES + 255) / 256, 256, 0, stream>>>(cnt, cursor, out, bfc2, bnsumAll, bv4);
    k_deg<<<(E_TOTAL + 255) / 256, 256, 0, stream>>>(intra, inter, cnt);
    k_scan1<<<SCAN_B, 256, 0, stream>>>(cnt, scanp, bsums, dinv);
    k_scan2<<<1, 256, 0, stream>>>(bsums, SCAN_B);
    k_scan3<<<SCAN_B, 256, 0, stream>>>(scanp, bsums, rowptr);
    k_scatter<<<(E_TOTAL + 255) / 256, 256, 0, stream>>>(intra, inter, rowptr, cursor, dinv, srcs, coef);
    k_concatW<<<(70 * 210 + 255) / 256, 256, 0, stream>>>(Wq, bq, Wk, bk, Wv, bv, Wcat, bcat);
    k_wprep<<<((256 / 16) * (128 / 32) * 64 + 255) / 256, 256, 0, stream>>>(W[1], Wf2, 128, 256, nullptr);
    k_wprep<<<((512 / 16) * (256 / 32) * 64 + 255) / 256, 256, 0, stream>>>(W[2], Wf3, 256, 512, nullptr);

    auto BN = [&](int layer) { return bnsumAll + layer * 1024; };
    auto AL = [&](int layer) { return alphaAll + layer * 512; };
    auto BE = [&](int layer) { return betaAll + layer * 512; };
    auto bn_final = [&](int layer, int d) {
        k_bn_final<<<1, 512, 0, stream>>>(BN(layer), gW[layer], beW[layer], AL(layer), BE(layer), d);
    };

    const int GB64 = (N_NODES + 63) / 64;
    const int GB128 = (N_NODES + 127) / 128;
    const int AGG4 = (N_NODES + 3) / 4;
    const int AGG8 = (N_NODES + 7) / 8;

    // L1: 35 -> 128 (aggregate-first), relu then bn-stats
    k_agg_small<<<AGG4, 256, 0, stream>>>(x, bufM, rowptr, srcs, coef, dinv, nullptr);
    k_gemm<<<dim3(2, GB64), 256, 0, stream>>>(bufM, W[0], bW[0], bufA, N_NODES, 35, 128, 1, nullptr, nullptr, 0);
    k_bn_stats<<<128, 256, 0, stream>>>(bufA, BN(0), 128);
    bn_final(0, 128);
    // L2: 128 -> 256 (aggregate-first, BN1 folded via end-affine; stats fused into GEMM epilogue)
    k_agg_vec<<<AGG8, 256, 0, stream>>>(bufA, bufM, rowptr, srcs, coef, dinv, AL(0), BE(0), nullptr, 128, 5);
    k_gemm_mfma<<<dim3(2, GB128), 256, 0, stream>>>(bufM, Wf2, bW[1], bufB, N_NODES, 128, 256, 1,
                                                    nullptr, nullptr, BN(1));
    bn_final(1, 256);
    // L3: 256 -> 512 (aggregate-first, BN2 folded; stats fused)
    k_agg_vec<<<AGG4, 256, 0, stream>>>(bufB, bufM, rowptr, srcs, coef, dinv, AL(1), BE(1), nullptr, 256, 6);
    k_gemm_mfma<<<dim3(4, GB128), 256, 0, stream>>>(bufM, Wf3, bW[2], bufA, N_NODES, 256, 512, 1,
                                                    nullptr, nullptr, BN(2));
    bn_final(2, 512);
    // W4 prep with BN3 folded into rows: (a3.v+b3)@W4 = v@(a3.W4) + b3@W4
    k_wprep<<<((256 / 16) * (512 / 32) * 64 + 255) / 256, 256, 0, stream>>>(W[3], Wf4, 512, 256, AL(2));
    k_bnbias<<<512 / 16, 256, 0, stream>>>(W[3], BE(2), bv4, 512, 256);
    // L4: 512 -> 256 (matmul-first, BN3 folded into W), aggregate + bias, stats
    k_gemm_mfma<<<dim3(2, GB128), 256, 0, stream>>>(bufA, Wf4, bv4, bufM, N_NODES, 512, 256, 0,
                                                    nullptr, nullptr, nullptr);
    k_agg_vec<<<AGG4, 256, 0, stream>>>(bufM, bufB, rowptr, srcs, coef, dinv, nullptr, nullptr, bW[3], 256, 6);
    k_bn_stats<<<256, 256, 0, stream>>>(bufB, BN(3), 256);
    bn_final(3, 256);
    // L5: 256 -> 35 (matmul-first, BN4+relu folded into A-read), aggregate, stats
    k_gemm<<<dim3(1, GB64), 256, 0, stream>>>(bufB, W[4], nullptr, bufM, N_NODES, 256, 35, 0, AL(3), BE(3), 1);
    k_agg_small<<<AGG4, 256, 0, stream>>>(bufM, bufA, rowptr, srcs, coef, dinv, bW[4]);
    k_bn_stats<<<35, 256, 0, stream>>>(bufA, BN(4), 35);
    bn_final(4, 35);

    // pooling per graph (BN5 folded into pool read)
    k_pool<<<BGRAPH, 256, 0, stream>>>(bufA, split, batch, lig, pro, AL(4), BE(4));

    // BiLSTM writes attention-input layout directly
    k_lstm<<<256, 192, 0, stream>>>(lig, pro, Wih_f, Whh_f, bih_f, bhh_f,
                                    Wih_b, Whh_b, bih_b, bhh_b, outb);

    // fused qkv projection: [17920,70] @ [70,210]
    k_gemm<<<dim3(4, (BGRAPH * TSEQ + 63) / 64), 256, 0, stream>>>(outb, Wcat, bcat, qkvb,
                                                                   BGRAPH * TSEQ, 70, 210, 0,
                                                                   nullptr, nullptr, 0);

    k_attention<<<BGRAPH, 256, 0, stream>>>(qkvb, osm);

    k_wsum<<<(70 * (FC1_OUT / 4) + 255) / 256, 256, 0, stream>>>(Wfc1, wsum);
    k_fc<<<dim3(17, 16), 256, 0, stream>>>(osm, Wfc1, wsum, bfc1, Wfc2, out);
}

// Round 15
// 959.569 us; speedup vs baseline: 1.0175x; 1.0175x over previous
//
#include <hip/hip_runtime.h>

#define N_NODES 50000
#define DIM0 35
#define BGRAPH 128
#define TSEQ 140
#define EPSBN 1e-5f
#define E_TOTAL 400000
#define E_INTRA 300000
#define E_INTER 100000
#define FC1_OUT 4340

typedef __attribute__((ext_vector_type(8))) short s8v;
typedef __attribute__((ext_vector_type(4))) short s4v;
typedef __attribute__((ext_vector_type(4))) float f32x4;

static __device__ __forceinline__ unsigned short bf16_rne(float x) {
    unsigned int u = __float_as_uint(x);
    unsigned int r = (u + 0x7FFFu + ((u >> 16) & 1u)) >> 16;
    return (unsigned short)r;
}
static __device__ __forceinline__ void bf16_split(float x, unsigned short& h, unsigned short& l) {
    h = bf16_rne(x);
    float hf = __uint_as_float(((unsigned int)h) << 16);
    l = bf16_rne(x - hf);
}

static __device__ __forceinline__ void edge_sd(int e, const int* intra, const int* inter, int& s, int& d) {
    if (e < E_INTRA) { s = intra[e]; d = intra[E_INTRA + e]; }
    else { int k = e - E_INTRA; s = inter[k]; d = inter[E_INTER + k]; }
}

__global__ void k_init(int* cnt, int* cursor, float* out, const float* bfc2, float* bnsumAll, float* bv4) {
    int i = blockIdx.x * 256 + threadIdx.x;
    if (i < N_NODES) { cnt[i] = 0; cursor[i] = 0; }
    if (i < BGRAPH) out[i] = bfc2[0];
    if (i < 5 * 1024) bnsumAll[i] = 0.f;
    if (i < 256) bv4[i] = 0.f;
}

__global__ void k_deg(const int* intra, const int* inter, int* cnt) {
    int e = blockIdx.x * 256 + threadIdx.x;
    if (e >= E_TOTAL) return;
    int s, d; edge_sd(e, intra, inter, s, d);
    atomicAdd(&cnt[d], 1);
}

__global__ void k_scan1(const int* __restrict__ cnt, int* __restrict__ partial, int* __restrict__ blocksum,
                        float* __restrict__ dinv) {
    __shared__ int buf[256];
    int t = threadIdx.x;
    int i = blockIdx.x * 256 + t;
    int v = (i < N_NODES) ? cnt[i] : 0;
    if (i < N_NODES) dinv[i] = rsqrtf(1.0f + (float)v);
    buf[t] = v;
    __syncthreads();
    for (int off = 1; off < 256; off <<= 1) {
        int add = (t >= off) ? buf[t - off] : 0;
        __syncthreads();
        buf[t] += add;
        __syncthreads();
    }
    if (i < N_NODES) partial[i] = buf[t];
    if (t == 255) blocksum[blockIdx.x] = buf[255];
}

__global__ void k_scan2(int* blocksum, int nb) {
    __shared__ int buf[256];
    int t = threadIdx.x;
    buf[t] = (t < nb) ? blocksum[t] : 0;
    __syncthreads();
    for (int off = 1; off < 256; off <<= 1) {
        int add = (t >= off) ? buf[t - off] : 0;
        __syncthreads();
        buf[t] += add;
        __syncthreads();
    }
    if (t < nb) blocksum[t] = buf[t];
}

__global__ void k_scan3(const int* __restrict__ partial, const int* __restrict__ blocksum, int* __restrict__ rowptr) {
    int b = blockIdx.x;
    int i = b * 256 + threadIdx.x;
    if (i == 0) rowptr[0] = 0;
    if (i < N_NODES) {
        int off = (b == 0) ? 0 : blocksum[b - 1];
        rowptr[i + 1] = partial[i] + off;
    }
}

__global__ void k_scatter(const int* intra, const int* inter, const int* rowptr,
                          int* cursor, const float* dinv, int* srcs, float* coef) {
    int e = blockIdx.x * 256 + threadIdx.x;
    if (e >= E_TOTAL) return;
    int s, d; edge_sd(e, intra, inter, s, d);
    int p = rowptr[d] + atomicAdd(&cursor[d], 1);
    srcs[p] = s;
    coef[p] = dinv[s] * dinv[d];
}

// wave-per-node aggregate for d=35 (2-way ILP edge loop)
__global__ __launch_bounds__(256) void k_agg_small(const float* __restrict__ X, float* __restrict__ Z,
        const int* __restrict__ rowptr, const int* __restrict__ srcs, const float* __restrict__ coef,
        const float* __restrict__ dinv, const float* __restrict__ bias) {
    int wave = threadIdx.x >> 6, lane = threadIdx.x & 63;
    int i = blockIdx.x * 4 + wave;
    if (i >= N_NODES || lane >= DIM0) return;
    int b0 = __builtin_amdgcn_readfirstlane(rowptr[i]);
    int e1 = __builtin_amdgcn_readfirstlane(rowptr[i + 1]);
    float self = dinv[i] * dinv[i];
    float acc0 = X[(size_t)i * DIM0 + lane] * self;
    float acc1 = 0.f;
    if (bias) acc0 += bias[lane];
    int k = b0;
    for (; k + 1 < e1; k += 2) {
        int s0 = srcs[k], s1 = srcs[k + 1];
        float c0 = coef[k], c1 = coef[k + 1];
        acc0 += c0 * X[(size_t)s0 * DIM0 + lane];
        acc1 += c1 * X[(size_t)s1 * DIM0 + lane];
    }
    if (k < e1) acc0 += coef[k] * X[(size_t)srcs[k] * DIM0 + lane];
    Z[(size_t)i * DIM0 + lane] = acc0 + acc1;
}

// lane-group-per-node float4 aggregate. BN fold hoisted OUT of the edge loop:
//   Z = alpha (.) (self*x_i + sum cf*x_s) + beta * (self + sum cf) + bias
__global__ __launch_bounds__(256) void k_agg_vec(const float* __restrict__ X, float* __restrict__ Z,
        const int* __restrict__ rowptr, const int* __restrict__ srcs, const float* __restrict__ coef,
        const float* __restrict__ dinv, const float* __restrict__ alpha, const float* __restrict__ beta,
        const float* __restrict__ bias, int d, int lpshift) {
    int i = (blockIdx.x * 256 + threadIdx.x) >> lpshift;
    int lane_in = threadIdx.x & ((1 << lpshift) - 1);
    if (i >= N_NODES) return;
    int b0 = rowptr[i], e1 = rowptr[i + 1];
    if (lpshift == 6) {
        b0 = __builtin_amdgcn_readfirstlane(b0);
        e1 = __builtin_amdgcn_readfirstlane(e1);
    }
    float self = dinv[i] * dinv[i];
    int c = lane_in * 4;
    float4 xi = *(const float4*)&X[(size_t)i * d + c];
    float4 a0, a1;
    a0.x = self * xi.x; a0.y = self * xi.y; a0.z = self * xi.z; a0.w = self * xi.w;
    a1 = make_float4(0.f, 0.f, 0.f, 0.f);
    float cs0 = self, cs1 = 0.f;
    int k = b0;
    for (; k + 1 < e1; k += 2) {
        int s0 = srcs[k], s1 = srcs[k + 1];
        float c0 = coef[k], c1 = coef[k + 1];
        float4 x0 = *(const float4*)&X[(size_t)s0 * d + c];
        float4 x1 = *(const float4*)&X[(size_t)s1 * d + c];
        a0.x += c0 * x0.x; a0.y += c0 * x0.y; a0.z += c0 * x0.z; a0.w += c0 * x0.w;
        a1.x += c1 * x1.x; a1.y += c1 * x1.y; a1.z += c1 * x1.z; a1.w += c1 * x1.w;
        cs0 += c0; cs1 += c1;
    }
    if (k < e1) {
        int s0 = srcs[k];
        float c0 = coef[k];
        float4 x0 = *(const float4*)&X[(size_t)s0 * d + c];
        a0.x += c0 * x0.x; a0.y += c0 * x0.y; a0.z += c0 * x0.z; a0.w += c0 * x0.w;
        cs0 += c0;
    }
    float4 acc;
    acc.x = a0.x + a1.x; acc.y = a0.y + a1.y; acc.z = a0.z + a1.z; acc.w = a0.w + a1.w;
    float csum = cs0 + cs1;
    float4 z = acc;
    if (alpha) {
        float4 al = *(const float4*)&alpha[c];
        float4 be = *(const float4*)&beta[c];
        z.x = al.x * acc.x + be.x * csum;
        z.y = al.y * acc.y + be.y * csum;
        z.z = al.z * acc.z + be.z * csum;
        z.w = al.w * acc.w + be.w * csum;
    }
    if (bias) {
        float4 bi = *(const float4*)&bias[c];
        z.x += bi.x; z.y += bi.y; z.z += bi.z; z.w += bi.w;
    }
    *(float4*)&Z[(size_t)i * d + c] = z;
}

// small fp32 GEMM (64x64 tile) with optional BN fold + relu on A-load.
__global__ __launch_bounds__(256) void k_gemm(const float* __restrict__ A, const float* __restrict__ W,
                                              const float* __restrict__ bias, float* __restrict__ C,
                                              int Mrows, int K, int Ncols, int relu,
                                              const float* __restrict__ alphaA, const float* __restrict__ betaA,
                                              int reluA) {
    __shared__ float As[64][17];
    __shared__ float Ws[16][65];
    int tid = threadIdx.x;
    int tx = tid & 15, ty = tid >> 4;
    int row0 = blockIdx.y * 64, col0 = blockIdx.x * 64;
    float acc[4][4] = {};
    for (int k0 = 0; k0 < K; k0 += 16) {
        for (int l = tid; l < 1024; l += 256) {
            int m = l >> 4, kk = l & 15;
            int r = row0 + m, k = k0 + kk;
            float v = 0.f;
            if (r < Mrows && k < K) {
                v = A[(size_t)r * K + k];
                if (alphaA) {
                    v = alphaA[k] * v + betaA[k];
                    if (reluA) v = fmaxf(v, 0.f);
                }
            }
            As[m][kk] = v;
        }
        for (int l = tid; l < 1024; l += 256) {
            int kk = l >> 6, n = l & 63;
            int k = k0 + kk, c = col0 + n;
            Ws[kk][n] = (k < K && c < Ncols) ? W[(size_t)k * Ncols + c] : 0.f;
        }
        __syncthreads();
#pragma unroll
        for (int kk = 0; kk < 16; ++kk) {
            float a[4], w[4];
#pragma unroll
            for (int i2 = 0; i2 < 4; ++i2) a[i2] = As[ty * 4 + i2][kk];
#pragma unroll
            for (int j = 0; j < 4; ++j) w[j] = Ws[kk][tx * 4 + j];
#pragma unroll
            for (int i2 = 0; i2 < 4; ++i2)
#pragma unroll
                for (int j = 0; j < 4; ++j)
                    acc[i2][j] += a[i2] * w[j];
        }
        __syncthreads();
    }
    for (int i2 = 0; i2 < 4; ++i2) {
        int r = row0 + ty * 4 + i2;
        if (r >= Mrows) continue;
        for (int j = 0; j < 4; ++j) {
            int c = col0 + tx * 4 + j;
            if (c >= Ncols) continue;
            float v = acc[i2][j];
            if (bias) v += bias[c];
            if (relu) v = fmaxf(v, 0.f);
            C[(size_t)r * Ncols + c] = v;
        }
    }
}

// Preprocess W[K][N] fp32 -> MFMA-fragment bf16 hi/lo; optional per-k rowscale.
__global__ void k_wprep(const float* __restrict__ W, unsigned short* __restrict__ Wf, int K, int Ncols,
                        const float* __restrict__ rowscale) {
    int gid = blockIdx.x * 256 + threadIdx.x;
    int KT = K >> 5;
    int total = (Ncols >> 4) * KT * 64;
    if (gid >= total) return;
    int lane = gid & 63;
    int f = gid >> 6;
    int kt = f % KT, ntile = f / KT;
    int n = ntile * 16 + (lane & 15);
    int kb = kt * 32 + (lane >> 4) * 8;
    size_t base = (size_t)f * 1024 + lane * 8;
#pragma unroll
    for (int j = 0; j < 8; ++j) {
        float v = W[(size_t)(kb + j) * Ncols + n];
        if (rowscale) v *= rowscale[kb + j];
        unsigned short h, l;
        bf16_split(v, h, l);
        Wf[base + j] = h;
        Wf[base + 512 + j] = l;
    }
}

// bv[c] += sum_{k in block's 16-row slice} beta[k] * W[k][c]
__global__ void k_bnbias(const float* __restrict__ W, const float* __restrict__ beta,
                         float* __restrict__ bv, int K, int Ncols) {
    int c = threadIdx.x;
    if (c >= Ncols) return;
    int k0 = blockIdx.x * 16;
    float acc = 0.f;
#pragma unroll
    for (int k = 0; k < 16; ++k) acc += beta[k0 + k] * W[(size_t)(k0 + k) * Ncols + c];
    atomicAdd(&bv[c], acc);
}

// MFMA GEMM (round-10 double-buffered structure + bijective XCD-aware block
// swizzle so blocks sharing an A panel land on the same XCD's L2).
// 128x128 tile, 4 waves 2x2, W-fragment register double-buffer prefetch.
__global__ __launch_bounds__(256) void k_gemm_mfma(
    const float* __restrict__ A, const unsigned short* __restrict__ Wf,
    const float* __restrict__ bias, float* __restrict__ C,
    int Mrows, int K, int Ncols, int relu,
    const float* __restrict__ alphaA, const float* __restrict__ betaA,
    float* __restrict__ bnsum) {
    __shared__ unsigned short As[2][2][128][40];
    int tid = threadIdx.x;
    int lane = tid & 63, wave = tid >> 6;
    int wm = wave >> 1, wn = wave & 1;

    // bijective XCD swizzle (m204): dispatch index -> work id such that each
    // XCD owns a contiguous chunk of work ids (panel-sharers co-located).
    int npanels = gridDim.x;
    int nwg = gridDim.x * gridDim.y;
    int lin = blockIdx.y * gridDim.x + blockIdx.x;
    int q = nwg >> 3, rmd = nwg & 7;
    int xcd = lin & 7, pos = lin >> 3;
    int wid = (xcd < rmd ? xcd * (q + 1) : rmd * (q + 1) + (xcd - rmd) * q) + pos;
    int row0 = (wid / npanels) * 128;
    int nt0 = (wid % npanels) * 8;
    int KT = K >> 5;

    f32x4 acc[4][4];
#pragma unroll
    for (int a = 0; a < 4; ++a)
#pragma unroll
        for (int b = 0; b < 4; ++b) acc[a][b] = (f32x4)0.f;

    float4 reg[4];
    auto load_chunk = [&](int kt) {
#pragma unroll
        for (int l = 0; l < 4; ++l) {
            int i = tid + l * 256;
            int m = i >> 3, kv = (i & 7) * 4;
            int r = row0 + m;
            float4 v = make_float4(0.f, 0.f, 0.f, 0.f);
            if (r < Mrows) v = *(const float4*)&A[(size_t)r * K + kt * 32 + kv];
            reg[l] = v;
        }
    };
    auto store_chunk = [&](int buf, int kt) {
#pragma unroll
        for (int l = 0; l < 4; ++l) {
            int i = tid + l * 256;
            int m = i >> 3, kv = (i & 7) * 4;
            float4 v = reg[l];
            if (alphaA) {
                int kg = kt * 32 + kv;
                float4 al = *(const float4*)&alphaA[kg];
                float4 be = *(const float4*)&betaA[kg];
                v.x = al.x * v.x + be.x;
                v.y = al.y * v.y + be.y;
                v.z = al.z * v.z + be.z;
                v.w = al.w * v.w + be.w;
            }
            unsigned short h0, l0, h1, l1, h2, l2, h3, l3;
            bf16_split(v.x, h0, l0); bf16_split(v.y, h1, l1);
            bf16_split(v.z, h2, l2); bf16_split(v.w, h3, l3);
            s4v hv = {(short)h0, (short)h1, (short)h2, (short)h3};
            s4v lv = {(short)l0, (short)l1, (short)l2, (short)l3};
            *(s4v*)&As[buf][0][m][kv] = hv;
            *(s4v*)&As[buf][1][m][kv] = lv;
        }
    };
    auto loadW = [&](int kt, s8v (&bh)[4], s8v (&bl)[4]) {
#pragma unroll
        for (int nt = 0; nt < 4; ++nt) {
            int ntg = nt0 + wn * 4 + nt;
            size_t fb = ((size_t)(ntg * KT + kt)) * 1024 + lane * 8;
            bh[nt] = *(const s8v*)&Wf[fb];
            bl[nt] = *(const s8v*)&Wf[fb + 512];
        }
    };

    int mrow = wm * 64 + (lane & 15);
    int koff = (lane >> 4) * 8;

    s8v bhA[4], blA[4], bhB[4], blB[4];
    load_chunk(0);
    store_chunk(0, 0);
    loadW(0, bhA, blA);
    __syncthreads();

    auto phase = [&](int kt, int cur, s8v (&bh)[4], s8v (&bl)[4], s8v (&nbh)[4], s8v (&nbl)[4]) {
        if (kt + 1 < KT) {
            load_chunk(kt + 1);
            loadW(kt + 1, nbh, nbl);
        }
        s8v ah[4], alo[4];
#pragma unroll
        for (int mt = 0; mt < 4; ++mt) {
            ah[mt]  = *(const s8v*)&As[cur][0][mrow + mt * 16][koff];
            alo[mt] = *(const s8v*)&As[cur][1][mrow + mt * 16][koff];
        }
#pragma unroll
        for (int nt = 0; nt < 4; ++nt)
#pragma unroll
            for (int mt = 0; mt < 4; ++mt) {
                acc[mt][nt] = __builtin_amdgcn_mfma_f32_16x16x32_bf16(ah[mt], bh[nt], acc[mt][nt], 0, 0, 0);
                acc[mt][nt] = __builtin_amdgcn_mfma_f32_16x16x32_bf16(ah[mt], bl[nt], acc[mt][nt], 0, 0, 0);
                acc[mt][nt] = __builtin_amdgcn_mfma_f32_16x16x32_bf16(alo[mt], bh[nt], acc[mt][nt], 0, 0, 0);
            }
        if (kt + 1 < KT) store_chunk(cur ^ 1, kt + 1);
        __syncthreads();
    };

    for (int kt = 0; kt < KT; kt += 2) {
        phase(kt, 0, bhA, blA, bhB, blB);
        phase(kt + 1, 1, bhB, blB, bhA, blA);
    }

    // epilogue: nt innermost so the wave's 4 x 64B stores per row are contiguous in time
    int cbase = nt0 * 16 + wn * 64 + (lane & 15);
    float bia[4];
#pragma unroll
    for (int nt = 0; nt < 4; ++nt) bia[nt] = bias ? bias[cbase + nt * 16] : 0.f;
    float s1[4] = {0.f, 0.f, 0.f, 0.f}, s2[4] = {0.f, 0.f, 0.f, 0.f};
#pragma unroll
    for (int mt = 0; mt < 4; ++mt) {
        int rbase = row0 + wm * 64 + mt * 16 + (lane >> 4) * 4;
#pragma unroll
        for (int r = 0; r < 4; ++r) {
            int rg = rbase + r;
            if (rg < Mrows) {
#pragma unroll
                for (int nt = 0; nt < 4; ++nt) {
                    float v = acc[mt][nt][r] + bia[nt];
                    if (relu) v = fmaxf(v, 0.f);
                    C[(size_t)rg * Ncols + cbase + nt * 16] = v;
                    s1[nt] += v; s2[nt] += v * v;
                }
            }
        }
    }
    if (bnsum) {
#pragma unroll
        for (int nt = 0; nt < 4; ++nt) {
            float a = s1[nt], b = s2[nt];
            a += __shfl_xor(a, 16, 64);
            a += __shfl_xor(a, 32, 64);
            b += __shfl_xor(b, 16, 64);
            b += __shfl_xor(b, 32, 64);
            if (lane < 16) {
                atomicAdd(&bnsum[cbase + nt * 16], a);
                atomicAdd(&bnsum[Ncols + cbase + nt * 16], b);
            }
        }
    }
}

// scalar BN stats; launch <<<d, 256>>> so each thread owns one column slot
__global__ void k_bn_stats(const float* __restrict__ X, float* sums, int d) {
    long long total = (long long)N_NODES * d;
    int G = gridDim.x * blockDim.x;
    int gid = blockIdx.x * blockDim.x + threadIdx.x;
    int c = gid % d;
    float s1 = 0.f, s2 = 0.f;
    for (long long i = gid; i < total; i += G) {
        float v = X[i];
        s1 += v; s2 += v * v;
    }
    atomicAdd(&sums[c], s1);
    atomicAdd(&sums[d + c], s2);
}

__global__ void k_bn_final(const float* sums, const float* g, const float* be,
                           float* alpha, float* beta, int d) {
    int c = threadIdx.x;
    if (c >= d) return;
    float mean = sums[c] / (float)N_NODES;
    float var = sums[d + c] / (float)N_NODES - mean * mean;
    float a = g[c] * rsqrtf(var + EPSBN);
    alpha[c] = a;
    beta[c] = be[c] - mean * a;
}

__global__ void k_pool(const float* __restrict__ h, const int* __restrict__ split,
                       const int* __restrict__ batch, float* lig, float* pro,
                       const float* __restrict__ alpha, const float* __restrict__ beta) {
    int b = blockIdx.x;
    __shared__ float sl[DIM0], sp[DIM0];
    __shared__ int s_start, s_end;
    if (threadIdx.x < DIM0) { sl[threadIdx.x] = 0.f; sp[threadIdx.x] = 0.f; }
    if (threadIdx.x == 0) {
        int lo = 0, hi = N_NODES;
        while (lo < hi) { int mid = (lo + hi) >> 1; if (batch[mid] < b) lo = mid + 1; else hi = mid; }
        s_start = lo;
        hi = N_NODES;
        while (lo < hi) { int mid = (lo + hi) >> 1; if (batch[mid] < b + 1) lo = mid + 1; else hi = mid; }
        s_end = lo;
    }
    __syncthreads();
    int start = s_start, end = s_end;
    for (int k = threadIdx.x; k < (end - start) * DIM0; k += blockDim.x) {
        int node = start + k / DIM0;
        int c = k % DIM0;
        float v = alpha[c] * h[(size_t)node * DIM0 + c] + beta[c];
        if (split[node] == 1) atomicAdd(&sp[c], v);
        else atomicAdd(&sl[c], v);
    }
    __syncthreads();
    if (threadIdx.x < DIM0) {
        lig[b * DIM0 + threadIdx.x] = sl[threadIdx.x];
        pro[b * DIM0 + threadIdx.x] = sp[threadIdx.x];
    }
}

__global__ __launch_bounds__(192) void k_lstm(
    const float* __restrict__ lig, const float* __restrict__ pro,
    const float* __restrict__ Wih_f, const float* __restrict__ Whh_f,
    const float* __restrict__ bih_f, const float* __restrict__ bhh_f,
    const float* __restrict__ Wih_b, const float* __restrict__ Whh_b,
    const float* __restrict__ bih_b, const float* __restrict__ bhh_b,
    float* __restrict__ outb) {
    int blk = blockIdx.x;
    int dir = blk >> 7;
    int b = blk & 127;
    const float* Wih = dir ? Wih_b : Wih_f;
    const float* Whh = dir ? Whh_b : Whh_f;
    const float* bih = dir ? bih_b : bih_f;
    const float* bhh = dir ? bhh_b : bhh_f;

    __shared__ float h_lds[DIM0];
    __shared__ float x_lds[2][DIM0];
    __shared__ float gate_lds[4 * DIM0];
    int t = threadIdx.x;
    float wih[DIM0], whh[DIM0], bsum = 0.f;
    if (t < 4 * DIM0) {
#pragma unroll
        for (int j = 0; j < DIM0; ++j) { wih[j] = Wih[t * DIM0 + j]; whh[j] = Whh[t * DIM0 + j]; }
        bsum = bih[t] + bhh[t];
    }
    if (t < DIM0) {
        x_lds[0][t] = lig[b * DIM0 + t];
        x_lds[1][t] = pro[b * DIM0 + t];
        h_lds[t] = 0.f;
    }
    float c_reg = 0.f;
    __syncthreads();
    for (int step = 0; step < TSEQ; ++step) {
        int tt = dir ? (TSEQ - 1 - step) : step;
        if (t < 4 * DIM0) {
            float acc0 = bsum, acc1 = 0.f;
            if (tt < 2) {
#pragma unroll
                for (int j = 0; j < DIM0; ++j) acc0 += wih[j] * x_lds[tt][j];
            }
#pragma unroll
            for (int j = 0; j < DIM0 - 1; j += 2) {
                acc0 += whh[j] * h_lds[j];
                acc1 += whh[j + 1] * h_lds[j + 1];
            }
            acc0 += whh[DIM0 - 1] * h_lds[DIM0 - 1];
            gate_lds[t] = acc0 + acc1;
        }
        __syncthreads();
        if (t < DIM0) {
            float gi = gate_lds[t], gf = gate_lds[DIM0 + t];
            float gg = gate_lds[2 * DIM0 + t], go = gate_lds[3 * DIM0 + t];
            float si = 1.f / (1.f + expf(-gi));
            float sf = 1.f / (1.f + expf(-gf));
            float so = 1.f / (1.f + expf(-go));
            c_reg = sf * c_reg + si * tanhf(gg);
            float hv = so * tanhf(c_reg);
            h_lds[t] = hv;
            outb[((size_t)b * TSEQ + tt) * 70 + dir * DIM0 + t] = hv;
        }
        __syncthreads();
    }
}

__global__ void k_concatW(const float* __restrict__ Wq, const float* __restrict__ bq,
                          const float* __restrict__ Wk, const float* __restrict__ bk,
                          const float* __restrict__ Wv, const float* __restrict__ bv,
                          float* __restrict__ Wcat, float* __restrict__ bcat) {
    int idx = blockIdx.x * 256 + threadIdx.x;
    if (idx < 70 * 210) {
        int k = idx / 210, col = idx % 210;
        int g = col / 70, j = col % 70;
        const float* Wsrc = (g == 0) ? Wq : ((g == 1) ? Wk : Wv);
        Wcat[idx] = Wsrc[k * 70 + j];
    }
    if (idx < 210) {
        int g = idx / 70, j = idx % 70;
        const float* bsrc = (g == 0) ? bq : ((g == 1) ? bk : bv);
        bcat[idx] = bsrc[j];
    }
}

__global__ void k_attention(const float* __restrict__ qkv, float* __restrict__ osm) {
    int b = blockIdx.x;
    __shared__ float q0[70], q1[70], s[TSEQ];
    __shared__ float s00_s, s01_s, ssum_s;
    int t = threadIdx.x;
    const float* base = qkv + (size_t)b * TSEQ * 210;
    if (t < 70) {
        q0[t] = base[0 * 210 + t];
        q1[t] = base[1 * 210 + t];
    }
    __syncthreads();
    const float scale = rsqrtf(70.f);
    if (t < TSEQ) {
        const float* krow = base + (size_t)t * 210 + 70;
        float acc = 0.f;
        for (int j = 0; j < 70; ++j) acc += q1[j] * krow[j];
        s[t] = acc * scale;
    } else if (t == TSEQ || t == TSEQ + 1) {
        int kk = t - TSEQ;
        const float* krow = base + (size_t)kk * 210 + 70;
        float acc = 0.f;
        for (int j = 0; j < 70; ++j) acc += q0[j] * krow[j];
        if (kk) s01_s = acc * scale; else s00_s = acc * scale;
    }
    __syncthreads();
    if (t == 0) {
        float mx = -1e30f;
        for (int i = 0; i < TSEQ; ++i) if (i != 1) mx = fmaxf(mx, s[i]);
        float sum = 0.f;
        for (int i = 0; i < TSEQ; ++i) {
            float e = (i == 1) ? 0.f : expf(s[i] - mx);
            s[i] = e; sum += e;
        }
        ssum_s = sum;
    }
    __syncthreads();
    if (t < 70) {
        float inv = 1.f / ssum_s;
        float acc = 0.f;
        for (int i = 0; i < TSEQ; ++i) acc += s[i] * base[(size_t)i * 210 + 140 + t];
        float o1v = acc * inv;
        float m0 = fmaxf(s00_s, s01_s);
        float e0 = expf(s00_s - m0), e1 = expf(s01_s - m0);
        float w0 = e0 / (e0 + e1), w1 = e1 / (e0 + e1);
        float v0 = base[0 * 210 + 140 + t];
        float v1 = base[1 * 210 + 140 + t];
        osm[b * 210 + t] = w0 * v0 + w1 * v1;
        osm[b * 210 + 70 + t] = o1v;
        osm[b * 210 + 140 + t] = v1;
    }
}

// Wsum[j][c] = sum_{tt=2..139} Wfc1[tt*70+j][c]  -- float4 over c (no atomics)
__global__ void k_wsum(const float* __restrict__ Wfc1, float* __restrict__ Wsum) {
    const int C4 = FC1_OUT / 4;  // 1085
    int idx = blockIdx.x * 256 + threadIdx.x;
    if (idx >= 70 * C4) return;
    int j = idx / C4, c4 = idx % C4;
    int c = c4 * 4;
    float4 acc = make_float4(0.f, 0.f, 0.f, 0.f);
    for (int tt = 2; tt < TSEQ; ++tt) {
        float4 w = *(const float4*)&Wfc1[((size_t)(tt * 70 + j)) * FC1_OUT + c];
        acc.x += w.x; acc.y += w.y; acc.z += w.z; acc.w += w.w;
    }
    *(float4*)&Wsum[(size_t)j * FC1_OUT + c] = acc;
}

__global__ __launch_bounds__(256) void k_fc(const float* __restrict__ osm, const float* __restrict__ Wfc1,
                                            const float* __restrict__ Wsum, const float* __restrict__ bfc1,
                                            const float* __restrict__ Wfc2, float* __restrict__ out) {
    __shared__ float olds[8][210];
    __shared__ float wred[4][8];
    int g = blockIdx.y;
    int c = blockIdx.x * 256 + threadIdx.x;
    for (int l = threadIdx.x; l < 8 * 210; l += 256)
        olds[l / 210][l % 210] = osm[(g * 8 + l / 210) * 210 + (l % 210)];
    __syncthreads();
    float acc[8] = {};
    if (c < FC1_OUT) {
        for (int j = 0; j < 140; ++j) {
            float w = Wfc1[(size_t)j * FC1_OUT + c];
#pragma unroll
            for (int b = 0; b < 8; ++b) acc[b] = fmaf(olds[b][j], w, acc[b]);
        }
        for (int j = 0; j < 70; ++j) {
            float w = Wsum[(size_t)j * FC1_OUT + c];
#pragma unroll
            for (int b = 0; b < 8; ++b) acc[b] = fmaf(olds[b][140 + j], w, acc[b]);
        }
        float bb = bfc1[c], pw = Wfc2[c];
#pragma unroll
        for (int b = 0; b < 8; ++b) acc[b] = fmaxf(acc[b] + bb, 0.f) * pw;
    }
#pragma unroll
    for (int b = 0; b < 8; ++b) {
        acc[b] += __shfl_down(acc[b], 32, 64);
        acc[b] += __shfl_down(acc[b], 16, 64);
        acc[b] += __shfl_down(acc[b], 8, 64);
        acc[b] += __shfl_down(acc[b], 4, 64);
        acc[b] += __shfl_down(acc[b], 2, 64);
        acc[b] += __shfl_down(acc[b], 1, 64);
    }
    int wave = threadIdx.x >> 6;
    if ((threadIdx.x & 63) == 0)
#pragma unroll
        for (int b = 0; b < 8; ++b) wred[wave][b] = acc[b];
    __syncthreads();
    if (threadIdx.x < 8) {
        float t = wred[0][threadIdx.x] + wred[1][threadIdx.x] + wred[2][threadIdx.x] + wred[3][threadIdx.x];
        atomicAdd(&out[g * 8 + threadIdx.x], t);
    }
}

extern "C" void kernel_launch(void* const* d_in, const int* in_sizes, int n_in,
                              void* d_out, int out_size, void* d_ws, size_t ws_size,
                              hipStream_t stream) {
    const float* x = (const float*)d_in[0];
    const int* intra = (const int*)d_in[1];
    const int* inter = (const int*)d_in[2];
    const int* split = (const int*)d_in[3];
    const int* batch = (const int*)d_in[4];
    const float *W[5], *bW[5], *gW[5], *beW[5];
    for (int i = 0; i < 5; ++i) {
        W[i]   = (const float*)d_in[5 + 4 * i];
        bW[i]  = (const float*)d_in[6 + 4 * i];
        gW[i]  = (const float*)d_in[7 + 4 * i];
        beW[i] = (const float*)d_in[8 + 4 * i];
    }
    const float* Wih_f = (const float*)d_in[25];
    const float* Whh_f = (const float*)d_in[26];
    const float* bih_f = (const float*)d_in[27];
    const float* bhh_f = (const float*)d_in[28];
    const float* Wih_b = (const float*)d_in[29];
    const float* Whh_b = (const float*)d_in[30];
    const float* bih_b = (const float*)d_in[31];
    const float* bhh_b = (const float*)d_in[32];
    const float* Wq = (const float*)d_in[33];
    const float* bq = (const float*)d_in[34];
    const float* Wk = (const float*)d_in[35];
    const float* bk = (const float*)d_in[36];
    const float* Wv = (const float*)d_in[37];
    const float* bv = (const float*)d_in[38];
    const float* Wfc1 = (const float*)d_in[39];
    const float* bfc1 = (const float*)d_in[40];
    const float* Wfc2 = (const float*)d_in[41];
    const float* bfc2 = (const float*)d_in[42];

    char* p = (char*)d_ws;
    auto carve = [&](size_t bytes) {
        char* r = p;
        p += (bytes + 255) & ~(size_t)255;
        return r;
    };
    float* bufA = (float*)carve((size_t)N_NODES * 512 * 4);
    float* bufB = (float*)carve((size_t)N_NODES * 256 * 4);
    float* bufM = (float*)carve((size_t)N_NODES * 256 * 4);
    float* dinv = (float*)carve((size_t)N_NODES * 4);
    int* cnt    = (int*)carve((size_t)N_NODES * 4);
    int* rowptr = (int*)carve((size_t)(N_NODES + 1) * 4);
    int* cursor = (int*)carve((size_t)N_NODES * 4);
    int* scanp  = (int*)carve((size_t)N_NODES * 4);
    int* bsums  = (int*)carve(256 * 4);
    int* srcs   = (int*)carve((size_t)E_TOTAL * 4);
    float* coef = (float*)carve((size_t)E_TOTAL * 4);
    float* bnsumAll = (float*)carve(5 * 1024 * 4);
    float* alphaAll = (float*)carve(5 * 512 * 4);
    float* betaAll  = (float*)carve(5 * 512 * 4);
    float* bv4  = (float*)carve(256 * 4);
    float* lig = (float*)carve((size_t)BGRAPH * DIM0 * 4);
    float* pro = (float*)carve((size_t)BGRAPH * DIM0 * 4);
    float* outb = (float*)carve((size_t)BGRAPH * TSEQ * 70 * 4);
    float* qkvb = (float*)carve((size_t)BGRAPH * TSEQ * 210 * 4);
    float* Wcat = (float*)carve((size_t)70 * 210 * 4);
    float* bcat = (float*)carve(210 * 4);
    float* osm = (float*)carve((size_t)BGRAPH * 210 * 4);
    float* wsum = (float*)carve((size_t)70 * FC1_OUT * 4);
    unsigned short* Wf2 = (unsigned short*)carve((size_t)128 * 256 * 2 * 2);
    unsigned short* Wf3 = (unsigned short*)carve((size_t)256 * 512 * 2 * 2);
    unsigned short* Wf4 = (unsigned short*)carve((size_t)512 * 256 * 2 * 2);

    float* out = (float*)d_out;

    const int SCAN_B = (N_NODES + 255) / 256;

    k_init<<<(N_NODES + 255) / 256, 256, 0, stream>>>(cnt, cursor, out, bfc2, bnsumAll, bv4);
    k_deg<<<(E_TOTAL + 255) / 256, 256, 0, stream>>>(intra, inter, cnt);
    k_scan1<<<SCAN_B, 256, 0, stream>>>(cnt, scanp, bsums, dinv);
    k_scan2<<<1, 256, 0, stream>>>(bsums, SCAN_B);
    k_scan3<<<SCAN_B, 256, 0, stream>>>(scanp, bsums, rowptr);
    k_scatter<<<(E_TOTAL + 255) / 256, 256, 0, stream>>>(intra, inter, rowptr, cursor, dinv, srcs, coef);
    k_concatW<<<(70 * 210 + 255) / 256, 256, 0, stream>>>(Wq, bq, Wk, bk, Wv, bv, Wcat, bcat);
    k_wprep<<<((256 / 16) * (128 / 32) * 64 + 255) / 256, 256, 0, stream>>>(W[1], Wf2, 128, 256, nullptr);
    k_wprep<<<((512 / 16) * (256 / 32) * 64 + 255) / 256, 256, 0, stream>>>(W[2], Wf3, 256, 512, nullptr);

    auto BN = [&](int layer) { return bnsumAll + layer * 1024; };
    auto AL = [&](int layer) { return alphaAll + layer * 512; };
    auto BE = [&](int layer) { return betaAll + layer * 512; };
    auto bn_final = [&](int layer, int d) {
        k_bn_final<<<1, 512, 0, stream>>>(BN(layer), gW[layer], beW[layer], AL(layer), BE(layer), d);
    };

    const int GB64 = (N_NODES + 63) / 64;
    const int GB128 = (N_NODES + 127) / 128;
    const int AGG4 = (N_NODES + 3) / 4;
    const int AGG8 = (N_NODES + 7) / 8;

    // L1: 35 -> 128 (aggregate-first), relu then bn-stats
    k_agg_small<<<AGG4, 256, 0, stream>>>(x, bufM, rowptr, srcs, coef, dinv, nullptr);
    k_gemm<<<dim3(2, GB64), 256, 0, stream>>>(bufM, W[0], bW[0], bufA, N_NODES, 35, 128, 1, nullptr, nullptr, 0);
    k_bn_stats<<<128, 256, 0, stream>>>(bufA, BN(0), 128);
    bn_final(0, 128);
    // L2: 128 -> 256 (aggregate-first, BN1 folded via end-affine; stats fused into GEMM epilogue)
    k_agg_vec<<<AGG8, 256, 0, stream>>>(bufA, bufM, rowptr, srcs, coef, dinv, AL(0), BE(0), nullptr, 128, 5);
    k_gemm_mfma<<<dim3(2, GB128), 256, 0, stream>>>(bufM, Wf2, bW[1], bufB, N_NODES, 128, 256, 1,
                                                    nullptr, nullptr, BN(1));
    bn_final(1, 256);
    // L3: 256 -> 512 (aggregate-first, BN2 folded; stats fused)
    k_agg_vec<<<AGG4, 256, 0, stream>>>(bufB, bufM, rowptr, srcs, coef, dinv, AL(1), BE(1), nullptr, 256, 6);
    k_gemm_mfma<<<dim3(4, GB128), 256, 0, stream>>>(bufM, Wf3, bW[2], bufA, N_NODES, 256, 512, 1,
                                                    nullptr, nullptr, BN(2));
    bn_final(2, 512);
    // W4 prep with BN3 folded into rows: (a3.v+b3)@W4 = v@(a3.W4) + b3@W4
    k_wprep<<<((256 / 16) * (512 / 32) * 64 + 255) / 256, 256, 0, stream>>>(W[3], Wf4, 512, 256, AL(2));
    k_bnbias<<<512 / 16, 256, 0, stream>>>(W[3], BE(2), bv4, 512, 256);
    // L4: 512 -> 256 (matmul-first, BN3 folded into W), aggregate + bias, stats
    k_gemm_mfma<<<dim3(2, GB128), 256, 0, stream>>>(bufA, Wf4, bv4, bufM, N_NODES, 512, 256, 0,
                                                    nullptr, nullptr, nullptr);
    k_agg_vec<<<AGG4, 256, 0, stream>>>(bufM, bufB, rowptr, srcs, coef, dinv, nullptr, nullptr, bW[3], 256, 6);
    k_bn_stats<<<256, 256, 0, stream>>>(bufB, BN(3), 256);
    bn_final(3, 256);
    // L5: 256 -> 35 (matmul-first, BN4+relu folded into A-read), aggregate, stats
    k_gemm<<<dim3(1, GB64), 256, 0, stream>>>(bufB, W[4], nullptr, bufM, N_NODES, 256, 35, 0, AL(3), BE(3), 1);
    k_agg_small<<<AGG4, 256, 0, stream>>>(bufM, bufA, rowptr, srcs, coef, dinv, bW[4]);
    k_bn_stats<<<35, 256, 0, stream>>>(bufA, BN(4), 35);
    bn_final(4, 35);

    // pooling per graph (BN5 folded into pool read)
    k_pool<<<BGRAPH, 256, 0, stream>>>(bufA, split, batch, lig, pro, AL(4), BE(4));

    // BiLSTM writes attention-input layout directly
    k_lstm<<<256, 192, 0, stream>>>(lig, pro, Wih_f, Whh_f, bih_f, bhh_f,
                                    Wih_b, Whh_b, bih_b, bhh_b, outb);

    // fused qkv projection: [17920,70] @ [70,210]
    k_gemm<<<dim3(4, (BGRAPH * TSEQ + 63) / 64), 256, 0, stream>>>(outb, Wcat, bcat, qkvb,
                                                                   BGRAPH * TSEQ, 70, 210, 0,
                                                                   nullptr, nullptr, 0);

    k_attention<<<BGRAPH, 256, 0, stream>>>(qkvb, osm);

    k_wsum<<<(70 * (FC1_OUT / 4) + 255) / 256, 256, 0, stream>>>(Wfc1, wsum);
    k_fc<<<dim3(17, 16), 256, 0, stream>>>(osm, Wfc1, wsum, bfc1, Wfc2, out);
}